// Round 5
// baseline (320.440 us; speedup 1.0000x reference)
//
#include <hip/hip_runtime.h>
#include <stdint.h>

#define NHEADS 32
#define DHEAD  128
#define LQ     2048
#define PAGE   16
#define QTILE  64     // q rows per block (4 waves x 16)
#define KVB    32     // kv tokens per tile (= 2 pages)
#define KPAD   136    // 128 + 8 f16 pad

typedef _Float16 f16x8 __attribute__((ext_vector_type(8)));
typedef float    f32x4 __attribute__((ext_vector_type(4)));

__global__ __launch_bounds__(256, 2)
void paged_attn_kernel(const float* __restrict__ q,
                       const int*   __restrict__ Kp,      // int8 values widened to int32
                       const int*   __restrict__ Vp,      // int8 values widened to int32
                       const float* __restrict__ Kscale,  // f16 values widened to f32
                       const float* __restrict__ Vscale,
                       const int*   __restrict__ pages,
                       float* __restrict__ out)
{
    __shared__ _Float16 Ks[KVB][KPAD];            // row-major K tile (int values, exact)
    __shared__ __align__(16) _Float16 Vt[DHEAD][KVB];  // V^T, dequantized, XOR-swizzled
    __shared__ float    ksc[KVB];
    __shared__ _Float16 Ps[4][16][40];            // per-wave P 16x32 (+8 pad)

    const int tid  = threadIdx.x;
    const int w    = tid >> 6;
    const int lane = tid & 63;
    const int g    = lane >> 4;       // 0..3
    const int c    = lane & 15;       // 0..15

    const int bx = blockIdx.x;
    const int h  = bx & (NHEADS - 1);
    const int nQT = gridDim.x >> 5;
    const int qt = nQT - 1 - (bx >> 5);      // heavy blocks first
    const int q0 = qt * QTILE;

    // log2-domain softmax: fold log2(e) into the Q scale, use exp2 everywhere
    const float qscale = 0.08838834764831845f * 1.44269504088896340736f;

    // ---- Q fragments: A-operand layout (row=lane&15, k=(lane>>4)*8+i) ----
    f16x8 qf[4];
    {
        const int qrow = q0 + w * 16 + c;
        const float* qp = q + ((size_t)h * LQ + qrow) * DHEAD;
        #pragma unroll
        for (int t = 0; t < 4; ++t) {
            const float* p = qp + t * 32 + g * 8;
            #pragma unroll
            for (int i = 0; i < 8; ++i)
                qf[t][i] = (_Float16)(p[i] * qscale);
        }
    }

    f32x4 o_acc[8];
    #pragma unroll
    for (int d = 0; d < 8; ++d) o_acc[d] = (f32x4){0.f, 0.f, 0.f, 0.f};
    float m_run[4], l_run[4];
    #pragma unroll
    for (int r = 0; r < 4; ++r) { m_run[r] = -1e30f; l_run[r] = 0.f; }

    const int ntiles = 2 * qt + 2;
    const int skv = tid >> 3;                // staging kv row 0..31
    const int sa  = tid & 7;                 // staging d-chunk 0..7 (16 ints each)

    char* vtb = (char*)&Vt[0][0];

    // ---- T14 async-STAGE: prefetch into regs, convert+write next iter ----
    auto issue = [&](int tile, int4* krD, int4* vrD, float& ksD, float& vsD) {
        const int t_glob = tile * KVB + skv;
        const int pg  = pages[t_glob >> 4];
        const int tok = t_glob & 15;
        const size_t base = (((size_t)pg * PAGE + tok) * NHEADS + h) * DHEAD + sa * 16;
        const int4* kp4 = (const int4*)(Kp + base);
        const int4* vp4 = (const int4*)(Vp + base);
        #pragma unroll
        for (int j = 0; j < 4; ++j) { krD[j] = kp4[j]; vrD[j] = vp4[j]; }
        vsD = Vscale[pg * NHEADS + h];           // per-thread: this kv row's V scale
        if (tid < KVB) {
            const int pg2 = pages[(tile * KVB + tid) >> 4];
            ksD = Kscale[pg2 * NHEADS + h];
        }
    };

    int4 krA[4], vrA[4]; float kscA = 0.f, vsrA = 0.f;
    int4 krB[4], vrB[4]; float kscB = 0.f, vsrB = 0.f;
    issue(0, krA, vrA, kscA, vsrA);

    for (int tile = 0; tile < ntiles; ++tile) {
        const int kv0 = tile * KVB;

        // ---- convert staged regs -> LDS ----
        {
            const int* ki = (const int*)krA;
            const int* vi = (const int*)vrA;
            // K: exact int -> f16, row-major (K page-scale applied post-QK^T)
            f16x8 klo, khi;
            #pragma unroll
            for (int i = 0; i < 8; ++i) {
                klo[i] = (_Float16)ki[i];
                khi[i] = (_Float16)ki[8 + i];
            }
            *(f16x8*)&Ks[skv][sa * 16]     = klo;
            *(f16x8*)&Ks[skv][sa * 16 + 8] = khi;
            // V: dequantized (int * vscale), transposed + XOR-swizzled store.
            // Vt[dcol][kv]; swizzle: byte ^= ((dcol>>3)&7)<<4 (rule 21: both sides)
            #pragma unroll
            for (int j = 0; j < 16; ++j) {
                const int dcol = sa * 16 + j;
                unsigned off = (unsigned)(dcol * (KVB * 2) + skv * 2);
                off ^= (unsigned)(((dcol >> 3) & 7) << 4);
                *(_Float16*)(vtb + off) = (_Float16)((float)vi[j] * vsrA);
            }
            if (tid < KVB) ksc[tid] = kscA;
        }
        __syncthreads();

        // issue next tile's loads now; latency hides under this tile's compute
        if (tile + 1 < ntiles) issue(tile + 1, krB, vrB, kscB, vsrB);

        const int q_wave_max = q0 + w * 16 + 15;
        if (kv0 <= q_wave_max) {             // wave-uniform causal skip
            // ---- QK^T: S[16q x 32kv] ----
            f32x4 s[2];
            #pragma unroll
            for (int nt = 0; nt < 2; ++nt) {
                s[nt] = (f32x4){0.f, 0.f, 0.f, 0.f};
                #pragma unroll
                for (int t = 0; t < 4; ++t) {
                    f16x8 kf = *(const f16x8*)&Ks[nt * 16 + c][t * 32 + g * 8];
                    s[nt] = __builtin_amdgcn_mfma_f32_16x16x32_f16(qf[t], kf, s[nt], 0, 0, 0);
                }
            }
            // ---- K page-scale per column + causal mask (log2 domain) ----
            const float ks0 = ksc[c],  ks1 = ksc[16 + c];
            const int kvg0 = kv0 + c, kvg1 = kv0 + 16 + c;
            const int qg   = q0 + w * 16 + g * 4;   // C-frag: row = 4g+r, col = c

            float tmax[4];
            #pragma unroll
            for (int r = 0; r < 4; ++r) {
                float s0 = s[0][r] * ks0;
                float s1 = s[1][r] * ks1;
                if (kvg0 > qg + r) s0 = -1e30f;
                if (kvg1 > qg + r) s1 = -1e30f;
                s[0][r] = s0; s[1][r] = s1;
                tmax[r] = fmaxf(s0, s1);
            }
            #pragma unroll
            for (int off = 1; off < 16; off <<= 1) {
                #pragma unroll
                for (int r = 0; r < 4; ++r)
                    tmax[r] = fmaxf(tmax[r], __shfl_xor(tmax[r], off, 64));
            }
            // ---- online softmax update (exp2) ----
            float alpha[4], rsum[4], p0[4], p1[4];
            #pragma unroll
            for (int r = 0; r < 4; ++r) {
                const float mn = fmaxf(m_run[r], tmax[r]);
                alpha[r] = exp2f(m_run[r] - mn);
                m_run[r] = mn;
                p0[r] = exp2f(s[0][r] - mn);
                p1[r] = exp2f(s[1][r] - mn);
                rsum[r] = p0[r] + p1[r];
            }
            #pragma unroll
            for (int off = 1; off < 16; off <<= 1) {
                #pragma unroll
                for (int r = 0; r < 4; ++r)
                    rsum[r] += __shfl_xor(rsum[r], off, 64);
            }
            #pragma unroll
            for (int r = 0; r < 4; ++r)
                l_run[r] = l_run[r] * alpha[r] + rsum[r];
            #pragma unroll
            for (int d = 0; d < 8; ++d)
                #pragma unroll
                for (int r = 0; r < 4; ++r)
                    o_acc[d][r] *= alpha[r];

            // ---- P (unscaled, in [0,1]) -> LDS, C-layout -> A-layout ----
            #pragma unroll
            for (int r = 0; r < 4; ++r) {
                Ps[w][g * 4 + r][c]      = (_Float16)p0[r];
                Ps[w][g * 4 + r][16 + c] = (_Float16)p1[r];
            }
            asm volatile("s_waitcnt lgkmcnt(0)" ::: "memory");  // wave-internal fence
            f16x8 pf = *(const f16x8*)&Ps[w][c][g * 8];          // A-frag read

            // ---- PV: B-frag vf[i] = V[kv=g*8+i][dcol=d*16+c] = Vt[d*16+c][g*8+i] ----
            #pragma unroll
            for (int d = 0; d < 8; ++d) {
                const int dcol = d * 16 + c;
                unsigned off = (unsigned)(dcol * (KVB * 2) + g * 16);
                off ^= (unsigned)(((dcol >> 3) & 7) << 4);   // same swizzle as store
                f16x8 vf = *(const f16x8*)(vtb + off);
                o_acc[d] = __builtin_amdgcn_mfma_f32_16x16x32_f16(pf, vf, o_acc[d], 0, 0, 0);
            }
        }
        __syncthreads();   // protect LDS before next tile's staging writes

        if (tile + 1 < ntiles) {
            #pragma unroll
            for (int j = 0; j < 4; ++j) { krA[j] = krB[j]; vrA[j] = vrB[j]; }
            kscA = kscB; vsrA = vsrB;
        }
    }

    // ---- normalize + store ----
    const int qg = q0 + w * 16 + g * 4;
    float inv_l[4];
    #pragma unroll
    for (int r = 0; r < 4; ++r) inv_l[r] = 1.f / l_run[r];
    #pragma unroll
    for (int d = 0; d < 8; ++d) {
        #pragma unroll
        for (int r = 0; r < 4; ++r)
            out[((size_t)h * LQ + qg + r) * DHEAD + d * 16 + c] = o_acc[d][r] * inv_l[r];
    }
}

extern "C" void kernel_launch(void* const* d_in, const int* in_sizes, int n_in,
                              void* d_out, int out_size, void* d_ws, size_t ws_size,
                              hipStream_t stream) {
    (void)in_sizes; (void)n_in; (void)d_ws; (void)ws_size; (void)out_size;
    const float* qp = (const float*)d_in[0];
    const int*   kp = (const int*)d_in[1];    // int8 -> int32 per harness contract
    const int*   vp = (const int*)d_in[2];
    const float* ks = (const float*)d_in[3];  // f16 -> f32 per harness contract
    const float* vs = (const float*)d_in[4];
    const int*   pg = (const int*)d_in[5];
    float*       op = (float*)d_out;

    dim3 grid(NHEADS * (LQ / QTILE));   // 1024 blocks, h fastest-varying
    dim3 block(256);
    paged_attn_kernel<<<grid, block, 0, stream>>>(qp, kp, vp, ks, vs, pg, op);
}

// Round 6
// 315.802 us; speedup vs baseline: 1.0147x; 1.0147x over previous
//
#include <hip/hip_runtime.h>
#include <stdint.h>

#define NHEADS 32
#define DHEAD  128
#define LQ     2048
#define PAGE   16
#define QTILE  64     // q rows per q-tile (4 waves x 16)
#define NQT    32     // q-tiles total (LQ/QTILE)
#define KVB    32     // kv tokens per tile (= 2 pages)
#define KPAD   136    // 128 + 8 f16 pad

typedef _Float16 f16x8 __attribute__((ext_vector_type(8)));
typedef float    f32x4 __attribute__((ext_vector_type(4)));

__global__ __launch_bounds__(256, 2)
void paged_attn_kernel(const float* __restrict__ q,
                       const int*   __restrict__ Kp,      // int8 values widened to int32
                       const int*   __restrict__ Vp,      // int8 values widened to int32
                       const float* __restrict__ Kscale,  // f16 values widened to f32
                       const float* __restrict__ Vscale,
                       const int*   __restrict__ pages,
                       float* __restrict__ out)
{
    __shared__ _Float16 Ks[KVB][KPAD];                 // row-major K tile (int values)
    __shared__ __align__(16) _Float16 Vt[DHEAD][KVB];  // V^T, dequantized, XOR-swizzled
    __shared__ float    ksc[KVB];
    __shared__ _Float16 Ps[4][16][40];                 // per-wave P 16x32 (+8 pad)

    const int tid  = threadIdx.x;
    const int w    = tid >> 6;
    const int lane = tid & 63;
    const int g    = lane >> 4;       // 0..3
    const int c    = lane & 15;       // 0..15

    const int bx = blockIdx.x;
    const int h  = bx & (NHEADS - 1);
    const int p  = bx >> 5;                  // pair id 0..15
    const int qa = p, qb = NQT - 1 - p;      // balanced causal pair: work = 66 tiles/block
    const int q0a = qa * QTILE, q0b = qb * QTILE;

    // log2-domain softmax: fold log2(e) into the Q scale, use exp2 everywhere
    const float qscale = 0.08838834764831845f * 1.44269504088896340736f;

    // ---- Q fragments for both q-tiles: A-layout (row=lane&15, k=(lane>>4)*8+i) ----
    f16x8 qfa[4], qfb[4];
    {
        const float* qpa = q + ((size_t)h * LQ + q0a + w * 16 + c) * DHEAD;
        const float* qpb = q + ((size_t)h * LQ + q0b + w * 16 + c) * DHEAD;
        #pragma unroll
        for (int t = 0; t < 4; ++t) {
            #pragma unroll
            for (int i = 0; i < 8; ++i) {
                qfa[t][i] = (_Float16)(qpa[t * 32 + g * 8 + i] * qscale);
                qfb[t][i] = (_Float16)(qpb[t * 32 + g * 8 + i] * qscale);
            }
        }
    }

    f32x4 oaccA[8], oaccB[8];
    float mA[4], lA[4], mB[4], lB[4];
    #pragma unroll
    for (int d = 0; d < 8; ++d) { oaccA[d] = (f32x4){0,0,0,0}; oaccB[d] = (f32x4){0,0,0,0}; }
    #pragma unroll
    for (int r = 0; r < 4; ++r) { mA[r] = mB[r] = -1e30f; lA[r] = lB[r] = 0.f; }

    const int ntiles = 2 * qb + 2;           // kv coverage for the heavy (hi) tile
    const int skv = tid >> 3;                // staging kv row 0..31
    const int sa  = tid & 7;                 // staging d-chunk 0..7 (16 ints each)

    char* vtb = (char*)&Vt[0][0];

    // ---- T14 async-STAGE: prefetch into regs, convert+write next iter ----
    auto issue = [&](int tile, int4* krD, int4* vrD, float& ksD, float& vsD) {
        const int t_glob = tile * KVB + skv;
        const int pg  = pages[t_glob >> 4];
        const int tok = t_glob & 15;
        const size_t base = (((size_t)pg * PAGE + tok) * NHEADS + h) * DHEAD + sa * 16;
        const int4* kp4 = (const int4*)(Kp + base);
        const int4* vp4 = (const int4*)(Vp + base);
        #pragma unroll
        for (int j = 0; j < 4; ++j) { krD[j] = kp4[j]; vrD[j] = vp4[j]; }
        vsD = Vscale[pg * NHEADS + h];           // this kv row's V scale
        if (tid < KVB) {
            const int pg2 = pages[(tile * KVB + tid) >> 4];
            ksD = Kscale[pg2 * NHEADS + h];
        }
    };

    // one compute pass over the staged tile for one q-tile's state
    auto compute = [&](int kv0, const f16x8* qf, int q0t,
                       f32x4* oacc, float* mr, float* lr) {
        // ---- QK^T: S[16q x 32kv] ----
        f32x4 s[2];
        #pragma unroll
        for (int nt = 0; nt < 2; ++nt) {
            s[nt] = (f32x4){0,0,0,0};
            #pragma unroll
            for (int t = 0; t < 4; ++t) {
                f16x8 kf = *(const f16x8*)&Ks[nt * 16 + c][t * 32 + g * 8];
                s[nt] = __builtin_amdgcn_mfma_f32_16x16x32_f16(qf[t], kf, s[nt], 0, 0, 0);
            }
        }
        // ---- K page-scale per column + causal mask (log2 domain) ----
        const float ks0 = ksc[c],  ks1 = ksc[16 + c];
        const int kvg0 = kv0 + c, kvg1 = kv0 + 16 + c;
        const int qg   = q0t + w * 16 + g * 4;   // C-frag: row = 4g+r, col = c

        float tmax[4];
        #pragma unroll
        for (int r = 0; r < 4; ++r) {
            float s0 = s[0][r] * ks0;
            float s1 = s[1][r] * ks1;
            if (kvg0 > qg + r) s0 = -1e30f;
            if (kvg1 > qg + r) s1 = -1e30f;
            s[0][r] = s0; s[1][r] = s1;
            tmax[r] = fmaxf(s0, s1);
        }
        #pragma unroll
        for (int off = 1; off < 16; off <<= 1)
            #pragma unroll
            for (int r = 0; r < 4; ++r)
                tmax[r] = fmaxf(tmax[r], __shfl_xor(tmax[r], off, 64));
        // ---- online softmax update (exp2) ----
        float alpha[4], rsum[4], p0[4], p1[4];
        #pragma unroll
        for (int r = 0; r < 4; ++r) {
            const float mn = fmaxf(mr[r], tmax[r]);
            alpha[r] = exp2f(mr[r] - mn);
            mr[r] = mn;
            p0[r] = exp2f(s[0][r] - mn);
            p1[r] = exp2f(s[1][r] - mn);
            rsum[r] = p0[r] + p1[r];
        }
        #pragma unroll
        for (int off = 1; off < 16; off <<= 1)
            #pragma unroll
            for (int r = 0; r < 4; ++r)
                rsum[r] += __shfl_xor(rsum[r], off, 64);
        #pragma unroll
        for (int r = 0; r < 4; ++r)
            lr[r] = lr[r] * alpha[r] + rsum[r];
        #pragma unroll
        for (int d = 0; d < 8; ++d)
            #pragma unroll
            for (int r = 0; r < 4; ++r)
                oacc[d][r] *= alpha[r];

        // ---- P (in [0,1]) -> LDS, C-layout -> A-layout (wave-private buffer) ----
        #pragma unroll
        for (int r = 0; r < 4; ++r) {
            Ps[w][g * 4 + r][c]      = (_Float16)p0[r];
            Ps[w][g * 4 + r][16 + c] = (_Float16)p1[r];
        }
        asm volatile("s_waitcnt lgkmcnt(0)" ::: "memory");  // wave-internal fence
        f16x8 pf = *(const f16x8*)&Ps[w][c][g * 8];          // A-frag read

        // ---- PV: vf[i] = V[kv=g*8+i][dcol=d*16+c] = Vt[d*16+c][g*8+i] ----
        #pragma unroll
        for (int d = 0; d < 8; ++d) {
            const int dcol = d * 16 + c;
            unsigned off = (unsigned)(dcol * (KVB * 2) + g * 16);
            off ^= (unsigned)(((dcol >> 3) & 7) << 4);   // same swizzle as store
            f16x8 vf = *(const f16x8*)(vtb + off);
            oacc[d] = __builtin_amdgcn_mfma_f32_16x16x32_f16(pf, vf, oacc[d], 0, 0, 0);
        }
    };

    int4 krA[4], vrA[4]; float kscA = 0.f, vsrA = 0.f;
    int4 krB[4], vrB[4]; float kscB = 0.f, vsrB = 0.f;
    issue(0, krA, vrA, kscA, vsrA);

    for (int tile = 0; tile < ntiles; ++tile) {
        const int kv0 = tile * KVB;

        // ---- convert staged regs -> LDS ----
        {
            const int* ki = (const int*)krA;
            const int* vi = (const int*)vrA;
            f16x8 klo, khi;
            #pragma unroll
            for (int i = 0; i < 8; ++i) {
                klo[i] = (_Float16)ki[i];
                khi[i] = (_Float16)ki[8 + i];
            }
            *(f16x8*)&Ks[skv][sa * 16]     = klo;
            *(f16x8*)&Ks[skv][sa * 16 + 8] = khi;
            // V: dequantized, transposed + XOR-swizzled (rule 21: both sides)
            #pragma unroll
            for (int j = 0; j < 16; ++j) {
                const int dcol = sa * 16 + j;
                unsigned off = (unsigned)(dcol * (KVB * 2) + skv * 2);
                off ^= (unsigned)(((dcol >> 3) & 7) << 4);
                *(_Float16*)(vtb + off) = (_Float16)((float)vi[j] * vsrA);
            }
            if (tid < KVB) ksc[tid] = kscA;
        }
        __syncthreads();

        if (tile + 1 < ntiles) issue(tile + 1, krB, vrB, kscB, vsrB);

        // hi q-tile (active for nearly all staged tiles)
        if (kv0 <= q0b + w * 16 + 15)
            compute(kv0, qfb, q0b, oaccB, mB, lB);
        // lo q-tile (active for the first 2p+2 tiles only)
        if (kv0 <= q0a + w * 16 + 15)
            compute(kv0, qfa, q0a, oaccA, mA, lA);

        __syncthreads();   // protect LDS before next tile's staging writes

        if (tile + 1 < ntiles) {
            #pragma unroll
            for (int j = 0; j < 4; ++j) { krA[j] = krB[j]; vrA[j] = vrB[j]; }
            kscA = kscB; vsrA = vsrB;
        }
    }

    // ---- normalize + store both q-tiles ----
    #pragma unroll
    for (int r = 0; r < 4; ++r) { lA[r] = 1.f / lA[r]; lB[r] = 1.f / lB[r]; }
    const int qgA = q0a + w * 16 + g * 4;
    const int qgB = q0b + w * 16 + g * 4;
    #pragma unroll
    for (int d = 0; d < 8; ++d) {
        #pragma unroll
        for (int r = 0; r < 4; ++r) {
            out[((size_t)h * LQ + qgA + r) * DHEAD + d * 16 + c] = oaccA[d][r] * lA[r];
            out[((size_t)h * LQ + qgB + r) * DHEAD + d * 16 + c] = oaccB[d][r] * lB[r];
        }
    }
}

extern "C" void kernel_launch(void* const* d_in, const int* in_sizes, int n_in,
                              void* d_out, int out_size, void* d_ws, size_t ws_size,
                              hipStream_t stream) {
    (void)in_sizes; (void)n_in; (void)d_ws; (void)ws_size; (void)out_size;
    const float* qp = (const float*)d_in[0];
    const int*   kp = (const int*)d_in[1];    // int8 -> int32 per harness contract
    const int*   vp = (const int*)d_in[2];
    const float* ks = (const float*)d_in[3];  // f16 -> f32 per harness contract
    const float* vs = (const float*)d_in[4];
    const int*   pg = (const int*)d_in[5];
    float*       op = (float*)d_out;

    dim3 grid(NHEADS * (NQT / 2));   // 512 balanced pair-blocks, h fastest-varying
    dim3 block(256);
    paged_attn_kernel<<<grid, block, 0, stream>>>(qp, kp, vp, ks, vs, pg, op);
}

// Round 8
// 265.322 us; speedup vs baseline: 1.2077x; 1.1903x over previous
//
#include <hip/hip_runtime.h>
#include <stdint.h>

#define NHEADS 32
#define DHEAD  128
#define LQ     2048
#define PAGE   16
#define QTILE  64     // q rows per q-tile (4 waves x 16)
#define NQT    32     // q-tiles total (LQ/QTILE)
#define KVB    32     // kv tokens per tile (= 2 pages)
#define KPAD   136    // 128 + 8 f16 pad

typedef _Float16 f16x8 __attribute__((ext_vector_type(8)));
typedef _Float16 f16x2v __attribute__((ext_vector_type(2)));
typedef float    f32x4 __attribute__((ext_vector_type(4)));

__global__ __launch_bounds__(256, 2)
void paged_attn_kernel(const float* __restrict__ q,
                       const int*   __restrict__ Kp,      // int8 widened to int32
                       const int*   __restrict__ Vp,      // int8 widened to int32
                       const float* __restrict__ Kscale,  // f16 widened to f32
                       const float* __restrict__ Vscale,
                       const int*   __restrict__ pages,
                       float* __restrict__ out)
{
    __shared__ _Float16 Ks[KVB][KPAD];                 // K tile, dequantized (ks folded)
    __shared__ __align__(16) _Float16 Vt[DHEAD][KVB];  // V^T, dequantized, XOR-swizzled

    const int tid  = threadIdx.x;
    const int w    = tid >> 6;
    const int lane = tid & 63;
    const int g    = lane >> 4;       // 0..3
    const int c    = lane & 15;       // 0..15

    const int bx = blockIdx.x;
    const int h  = bx & (NHEADS - 1);
    const int p  = bx >> 5;                  // pair id 0..15
    const int qa = p, qb = NQT - 1 - p;      // balanced causal pair
    const int q0a = qa * QTILE, q0b = qb * QTILE;

    // log2-domain softmax: fold log2(e) into the Q scale
    const float qscale = 0.08838834764831845f * 1.44269504088896340736f;

    // ---- Q fragments (A/B-layout: row/col = lane&15, k = (lane>>4)*8+i) ----
    f16x8 qfa[4], qfb[4];
    {
        const float* qpa = q + ((size_t)h * LQ + q0a + w * 16 + c) * DHEAD;
        const float* qpb = q + ((size_t)h * LQ + q0b + w * 16 + c) * DHEAD;
        #pragma unroll
        for (int t = 0; t < 4; ++t)
            #pragma unroll
            for (int i = 0; i < 8; ++i) {
                qfa[t][i] = (_Float16)(qpa[t * 32 + g * 8 + i] * qscale);
                qfb[t][i] = (_Float16)(qpb[t * 32 + g * 8 + i] * qscale);
            }
    }

    f32x4 oaccA[8], oaccB[8];
    #pragma unroll
    for (int d = 0; d < 8; ++d) { oaccA[d] = (f32x4){0,0,0,0}; oaccB[d] = (f32x4){0,0,0,0}; }
    float mA = -1e30f, lA = 0.f, mB = -1e30f, lB = 0.f;

    const int ntiles = 2 * qb + 2;
    const int skv = tid >> 3;                // staging kv row 0..31
    const int sa  = tid & 7;                 // staging d-chunk 0..7
    char* vtb = (char*)&Vt[0][0];

    auto issue = [&](int tile, int4* krD, int4* vrD, float& ksD, float& vsD) {
        const int t_glob = tile * KVB + skv;
        const int pg  = pages[t_glob >> 4];
        const int tok = t_glob & 15;
        const size_t base = (((size_t)pg * PAGE + tok) * NHEADS + h) * DHEAD + sa * 16;
        const int4* kp4 = (const int4*)(Kp + base);
        const int4* vp4 = (const int4*)(Vp + base);
        #pragma unroll
        for (int j = 0; j < 4; ++j) { krD[j] = kp4[j]; vrD[j] = vp4[j]; }
        ksD = Kscale[pg * NHEADS + h];
        vsD = Vscale[pg * NHEADS + h];
    };

    // Swapped-QK^T compute: S^T = mfma(K,Q) -> lane holds S[q=qW+c][kv=kv0+16nt+4g+r].
    // kf fragments are hoisted (shared by the two paired q-tiles).
    auto compute = [&](int kv0, const f16x8 (*kf)[4], const f16x8* qf, int q0t,
                       f32x4* oacc, float& mr, float& lr) {
        f32x4 s0 = (f32x4){0,0,0,0}, s1 = (f32x4){0,0,0,0};
        #pragma unroll
        for (int t = 0; t < 4; ++t) {
            s0 = __builtin_amdgcn_mfma_f32_16x16x32_f16(kf[0][t], qf[t], s0, 0, 0, 0);
            s1 = __builtin_amdgcn_mfma_f32_16x16x32_f16(kf[1][t], qf[t], s1, 0, 0, 0);
        }
        // causal mask: kv = kv0 + 16*nt + 4g + r  >  q = q0t + w*16 + c  -> masked
        const int dq = (q0t + w * 16 + c) - (kv0 + 4 * g);
        #pragma unroll
        for (int r = 0; r < 4; ++r) {
            if (r > dq)      s0[r] = -1e30f;
            if (r > dq - 16) s1[r] = -1e30f;
        }
        // row max: 7 in-lane + 2 shuffles (kv row spread over lanes {c,16+c,32+c,48+c})
        float tm = fmaxf(fmaxf(fmaxf(s0[0], s0[1]), fmaxf(s0[2], s0[3])),
                         fmaxf(fmaxf(s1[0], s1[1]), fmaxf(s1[2], s1[3])));
        tm = fmaxf(tm, __shfl_xor(tm, 16, 64));
        tm = fmaxf(tm, __shfl_xor(tm, 32, 64));
        const float mn    = fmaxf(mr, tm);
        const float alpha = exp2f(mr - mn);
        mr = mn;
        float p0[4], p1[4];
        #pragma unroll
        for (int r = 0; r < 4; ++r) {
            p0[r] = exp2f(s0[r] - mn);
            p1[r] = exp2f(s1[r] - mn);
        }
        float rs = ((p0[0] + p0[1]) + (p0[2] + p0[3])) +
                   ((p1[0] + p1[1]) + (p1[2] + p1[3]));
        rs += __shfl_xor(rs, 16, 64);
        rs += __shfl_xor(rs, 32, 64);
        lr = lr * alpha + rs;
        // alpha for o_acc rows q=4g+r lives in lane with (lane&15)==4g+r: src=20g+r
        float aR[4];
        #pragma unroll
        for (int r = 0; r < 4; ++r) aR[r] = __shfl(alpha, 20 * g + r, 64);
        #pragma unroll
        for (int d = 0; d < 8; ++d)
            #pragma unroll
            for (int r = 0; r < 4; ++r)
                oacc[d][r] *= aR[r];
        // ---- P redistribution to PV A-frag, fully in-register ----
        // lane holds P pairs w[nt][rp] = (kv=16nt+4g+2rp, +1) for q=c.
        // A-frag needs word j = (kv=8g+2j, +1): src word (nt=g>>1, rp=j&1),
        // src lane = (2*(g&1) + (j>>1))*16 + c.  [8g+2j == 16*(g>>1)+8*(g&1)+4*(j>>1)+2*(j&1)]
        f16x2v t0, t1, t2, t3;
        t0[0] = (_Float16)p0[0]; t0[1] = (_Float16)p0[1];
        t1[0] = (_Float16)p0[2]; t1[1] = (_Float16)p0[3];
        t2[0] = (_Float16)p1[0]; t2[1] = (_Float16)p1[1];
        t3[0] = (_Float16)p1[2]; t3[1] = (_Float16)p1[3];
        const int w00 = __builtin_bit_cast(int, t0);   // nt0, rp0
        const int w01 = __builtin_bit_cast(int, t1);   // nt0, rp1
        const int w10 = __builtin_bit_cast(int, t2);   // nt1, rp0
        const int w11 = __builtin_bit_cast(int, t3);   // nt1, rp1
        const int srcL = ((g & 1) << 5) | c;           // j=0,1
        const int srcH = srcL + 16;                    // j=2,3
        const int e0A = __shfl(w00, srcL, 64), e0B = __shfl(w10, srcL, 64);
        const int e1A = __shfl(w01, srcL, 64), e1B = __shfl(w11, srcL, 64);
        const int e2A = __shfl(w00, srcH, 64), e2B = __shfl(w10, srcH, 64);
        const int e3A = __shfl(w01, srcH, 64), e3B = __shfl(w11, srcH, 64);
        const bool hi = g >= 2;                        // receiver needs nt = g>>1
        uint4 aw;
        aw.x = (unsigned)(hi ? e0B : e0A);
        aw.y = (unsigned)(hi ? e1B : e1A);
        aw.z = (unsigned)(hi ? e2B : e2A);
        aw.w = (unsigned)(hi ? e3B : e3A);
        const f16x8 pa = __builtin_bit_cast(f16x8, aw);
        // ---- PV: vf[i] = Vt[dcol=d*16+c][kv=g*8+i] (swizzled) ----
        #pragma unroll
        for (int d = 0; d < 8; ++d) {
            const int dcol = d * 16 + c;
            unsigned off = (unsigned)(dcol * (KVB * 2) + g * 16);
            off ^= (unsigned)(((dcol >> 3) & 7) << 4);
            f16x8 vf = *(const f16x8*)(vtb + off);
            oacc[d] = __builtin_amdgcn_mfma_f32_16x16x32_f16(pa, vf, oacc[d], 0, 0, 0);
        }
    };

    int4 krA[4], vrA[4]; float ksrA = 0.f, vsrA = 0.f;
    int4 krB[4], vrB[4]; float ksrB = 0.f, vsrB = 0.f;
    issue(0, krA, vrA, ksrA, vsrA);

    for (int tile = 0; tile < ntiles; ++tile) {
        const int kv0 = tile * KVB;

        // ---- staged regs -> LDS (both K and V dequantized; scales folded) ----
        {
            const int* ki = (const int*)krA;
            const int* vi = (const int*)vrA;
            f16x8 klo, khi;
            #pragma unroll
            for (int i = 0; i < 8; ++i) {
                klo[i] = (_Float16)((float)ki[i]     * ksrA);
                khi[i] = (_Float16)((float)ki[8 + i] * ksrA);
            }
            *(f16x8*)&Ks[skv][sa * 16]     = klo;
            *(f16x8*)&Ks[skv][sa * 16 + 8] = khi;
            #pragma unroll
            for (int j = 0; j < 16; ++j) {
                const int dcol = sa * 16 + j;
                unsigned off = (unsigned)(dcol * (KVB * 2) + skv * 2);
                off ^= (unsigned)(((dcol >> 3) & 7) << 4);
                *(_Float16*)(vtb + off) = (_Float16)((float)vi[j] * vsrA);
            }
        }
        __syncthreads();

        if (tile + 1 < ntiles) issue(tile + 1, krB, vrB, ksrB, vsrB);

        // hoisted K fragments (shared by both paired computes)
        f16x8 kf[2][4];
        #pragma unroll
        for (int t = 0; t < 4; ++t) {
            kf[0][t] = *(const f16x8*)&Ks[c][t * 32 + g * 8];
            kf[1][t] = *(const f16x8*)&Ks[16 + c][t * 32 + g * 8];
        }

        if (kv0 <= q0b + w * 16 + 15)
            compute(kv0, kf, qfb, q0b, oaccB, mB, lB);
        if (kv0 <= q0a + w * 16 + 15)
            compute(kv0, kf, qfa, q0a, oaccA, mA, lA);

        __syncthreads();

        if (tile + 1 < ntiles) {
            #pragma unroll
            for (int j = 0; j < 4; ++j) { krA[j] = krB[j]; vrA[j] = vrB[j]; }
            ksrA = ksrB; vsrA = vsrB;
        }
    }

    // ---- normalize + store (l for row q=4g+r lives in lane 20g+r) ----
    float iA[4], iB[4];
    #pragma unroll
    for (int r = 0; r < 4; ++r) {
        iA[r] = 1.f / __shfl(lA, 20 * g + r, 64);
        iB[r] = 1.f / __shfl(lB, 20 * g + r, 64);
    }
    const int qgA = q0a + w * 16 + g * 4;
    const int qgB = q0b + w * 16 + g * 4;
    #pragma unroll
    for (int d = 0; d < 8; ++d)
        #pragma unroll
        for (int r = 0; r < 4; ++r) {
            out[((size_t)h * LQ + qgA + r) * DHEAD + d * 16 + c] = oaccA[d][r] * iA[r];
            out[((size_t)h * LQ + qgB + r) * DHEAD + d * 16 + c] = oaccB[d][r] * iB[r];
        }
}

extern "C" void kernel_launch(void* const* d_in, const int* in_sizes, int n_in,
                              void* d_out, int out_size, void* d_ws, size_t ws_size,
                              hipStream_t stream) {
    (void)in_sizes; (void)n_in; (void)d_ws; (void)ws_size; (void)out_size;
    const float* qp = (const float*)d_in[0];
    const int*   kp = (const int*)d_in[1];    // int8 -> int32 per harness contract
    const int*   vp = (const int*)d_in[2];
    const float* ks = (const float*)d_in[3];  // f16 -> f32 per harness contract
    const float* vs = (const float*)d_in[4];
    const int*   pg = (const int*)d_in[5];
    float*       op = (float*)d_out;

    dim3 grid(NHEADS * (NQT / 2));   // 512 balanced pair-blocks
    dim3 block(256);
    paged_attn_kernel<<<grid, block, 0, stream>>>(qp, kp, vp, ks, vs, pg, op);
}